// Round 1
// baseline (851.149 us; speedup 1.0000x reference)
//
#include <hip/hip_runtime.h>
#include <hip/hip_bf16.h>
#include <math.h>

constexpr int cB = 8, cNQ = 300, cC = 256, cH = 64, cW = 64, cHEADS = 8, cHD = 32;
constexpr int cHW = cH * cW;
constexpr float cSCALE = 0.1767766952966369f; // 32^-0.5

// out[m,n] = (dot(X[m,:], Wt[n,:]) + bias[n]) * scale   (M rows, 256x256 weight)
__global__ __launch_bounds__(256) void proj_rows_k(
    const float* __restrict__ X, const float* __restrict__ Wt,
    const float* __restrict__ bias, float* __restrict__ out, float scale) {
  __shared__ float xs[cC];
  int m = blockIdx.x;
  int n = threadIdx.x;
  xs[n] = X[(size_t)m * cC + n];
  __syncthreads();
  const float4* wrow = (const float4*)(Wt + (size_t)n * cC);
  float acc = 0.f;
#pragma unroll 8
  for (int k4 = 0; k4 < cC / 4; ++k4) {
    float4 w = wrow[k4];
    acc += xs[k4 * 4 + 0] * w.x + xs[k4 * 4 + 1] * w.y +
           xs[k4 * 4 + 2] * w.z + xs[k4 * 4 + 3] * w.w;
  }
  out[(size_t)m * cC + n] = (acc + bias[n]) * scale;
}

// pk[b,o,hw] = sum_c Wk[o,c]*key[b,c,hw] + bk[o]  (and same for v). z = b*2 + isv.
__global__ __launch_bounds__(256) void proj_kv_k(
    const float* __restrict__ key, const float* __restrict__ value,
    const float* __restrict__ Wk, const float* __restrict__ bk,
    const float* __restrict__ Wv, const float* __restrict__ bv,
    float* __restrict__ pk, float* __restrict__ pv) {
  int z = blockIdx.z;
  int b = z >> 1;
  bool isv = z & 1;
  const float* X = (isv ? value : key) + (size_t)b * cC * cHW;
  const float* Wm = isv ? Wv : Wk;
  const float* bb = isv ? bv : bk;
  float* out = (isv ? pv : pk) + (size_t)b * cC * cHW;
  int hw0 = blockIdx.x * 128;
  int o0 = blockIdx.y * 64;

  __shared__ float As[64][20];   // Wm tile [64 o][16 c], padded
  __shared__ float Bs[16][132];  // X tile  [16 c][128 hw], padded (132*4B keeps 16B align)
  int tid = threadIdx.x;
  int tx = tid & 31, ty = tid >> 5;

  float acc[8][4];
#pragma unroll
  for (int i = 0; i < 8; ++i)
#pragma unroll
    for (int j = 0; j < 4; ++j) acc[i][j] = 0.f;

  for (int c0 = 0; c0 < cC; c0 += 16) {
    {
      int row = tid >> 2, cg = (tid & 3) << 2;
      float4 v = *(const float4*)(Wm + (size_t)(o0 + row) * cC + c0 + cg);
      *(float4*)&As[row][cg] = v;
    }
    {
      int row = tid >> 4, col = (tid & 15) << 3;
      const float* src = X + (size_t)(c0 + row) * cHW + hw0 + col;
      *(float4*)&Bs[row][col] = *(const float4*)src;
      *(float4*)&Bs[row][col + 4] = *(const float4*)(src + 4);
    }
    __syncthreads();
#pragma unroll
    for (int kk = 0; kk < 16; ++kk) {
      float a[8], bv4[4];
#pragma unroll
      for (int j = 0; j < 4; ++j) bv4[j] = Bs[kk][tx + 32 * j];
#pragma unroll
      for (int i = 0; i < 8; ++i) a[i] = As[ty * 8 + i][kk];
#pragma unroll
      for (int i = 0; i < 8; ++i)
#pragma unroll
        for (int j = 0; j < 4; ++j) acc[i][j] += a[i] * bv4[j];
    }
    __syncthreads();
  }
#pragma unroll
  for (int i = 0; i < 8; ++i) {
    float bias = bb[o0 + ty * 8 + i];
#pragma unroll
    for (int j = 0; j < 4; ++j)
      out[(size_t)(o0 + ty * 8 + i) * cHW + hw0 + tx + 32 * j] = acc[i][j] + bias;
  }
}

// One wave per (b,q,head). Block = 4 waves = 4 heads; grid = B*NQ*2.
__global__ __launch_bounds__(256) void attn_k(
    const float* __restrict__ pq, const float* __restrict__ pk,
    const float* __restrict__ pv, const float* __restrict__ pts,
    float* __restrict__ out) {
  int gid = blockIdx.x;
  int pair = gid & 1;
  int bq = gid >> 1;
  int b = bq / cNQ, q = bq - b * cNQ;
  int tid = threadIdx.x;
  int wid = tid >> 6, lane = tid & 63;
  int n = pair * 4 + wid;

  __shared__ float q_s[128];
  __shared__ float attn_s[4][2][64];
  __shared__ float sptf[2];
  __shared__ int spti[4];
  if (tid < 128) q_s[tid] = pq[((size_t)b * cNQ + q) * cC + pair * 128 + tid];
  if (tid == 0) {
    float x = pts[((size_t)b * cNQ + q) * 2 + 0];
    float y = pts[((size_t)b * cNQ + q) * 2 + 1];
    float y0f = fminf(fmaxf(floorf(y), 0.f), (float)(cH - 1));
    float x0f = fminf(fmaxf(floorf(x), 0.f), (float)(cW - 1));
    sptf[0] = y - y0f;
    sptf[1] = x - x0f;
    spti[0] = (int)y0f;
    spti[1] = min((int)y0f + 1, cH - 1);
    spti[2] = (int)x0f;
    spti[3] = min((int)x0f + 1, cW - 1);
  }
  __syncthreads();
  float wy = sptf[0], wx = sptf[1];
  int y0 = spti[0], y1 = spti[1], x0 = spti[2], x1 = spti[3];

  const float* pkb = pk + ((size_t)b * cC + n * cHD) * cHW;
  const float* pvb = pv + ((size_t)b * cC + n * cHD) * cHW;

  // ---- logits: lane = position (w for rows, h for cols) ----
  float wrow = 0.f, wcol = 0.f;
#pragma unroll 4
  for (int d = 0; d < cHD; ++d) {
    float qd = q_s[wid * 32 + d];
    const float* pd = pkb + (size_t)d * cHW;
    float kr = pd[y0 * cW + lane] * (1.f - wy) + pd[y1 * cW + lane] * wy;
    float kc = pd[lane * cW + x0] * (1.f - wx) + pd[lane * cW + x1] * wx;
    wrow += qd * kr;
    wcol += qd * kc;
  }

  // ---- softmax over 128 values (2 per lane) ----
  float m = fmaxf(wrow, wcol);
#pragma unroll
  for (int s = 32; s > 0; s >>= 1) m = fmaxf(m, __shfl_xor(m, s, 64));
  float er = expf(wrow - m), ec = expf(wcol - m);
  float ssum = er + ec;
#pragma unroll
  for (int s = 32; s > 0; s >>= 1) ssum += __shfl_xor(ssum, s, 64);
  float inv = 1.f / ssum;
  attn_s[wid][0][lane] = er * inv;
  attn_s[wid][1][lane] = ec * inv;
  __syncthreads();

  // ---- PV: lane -> (d = lane&31, half = lane>>5), each handles 32 positions ----
  int d = lane & 31, half = lane >> 5;
  const float* pvd = pvb + (size_t)d * cHW;
  float acc = 0.f;
#pragma unroll 4
  for (int j = 0; j < 32; ++j) {
    int pos = half * 32 + j;
    float ar = attn_s[wid][0][pos], ac = attn_s[wid][1][pos];
    float vr = pvd[y0 * cW + pos] * (1.f - wy) + pvd[y1 * cW + pos] * wy;
    float vc = pvd[pos * cW + x0] * (1.f - wx) + pvd[pos * cW + x1] * wx;
    acc += ar * vr + ac * vc;
  }
  acc += __shfl_xor(acc, 32, 64);
  if (lane < 32) out[((size_t)b * cNQ + q) * cC + n * cHD + d] = acc;
}

extern "C" void kernel_launch(void* const* d_in, const int* in_sizes, int n_in,
                              void* d_out, int out_size, void* d_ws, size_t ws_size,
                              hipStream_t stream) {
  const float* query = (const float*)d_in[0];
  const float* key   = (const float*)d_in[1];
  const float* value = (const float*)d_in[2];
  const float* pts   = (const float*)d_in[3];
  const float* Wq = (const float*)d_in[4];
  const float* bq = (const float*)d_in[5];
  const float* Wk = (const float*)d_in[6];
  const float* bk = (const float*)d_in[7];
  const float* Wv = (const float*)d_in[8];
  const float* bv = (const float*)d_in[9];
  const float* Wo = (const float*)d_in[10];
  const float* bo = (const float*)d_in[11];
  float* out = (float*)d_out;

  float* pq = (float*)d_ws;                         // 614400
  float* pk = pq + (size_t)cB * cNQ * cC;           // 8388608
  float* pv = pk + (size_t)cB * cC * cHW;           // 8388608
  float* ao = pv + (size_t)cB * cC * cHW;           // 614400

  proj_rows_k<<<cB * cNQ, 256, 0, stream>>>(query, Wq, bq, pq, cSCALE);
  proj_kv_k<<<dim3(cHW / 128, cC / 64, cB * 2), 256, 0, stream>>>(
      key, value, Wk, bk, Wv, bv, pk, pv);
  attn_k<<<cB * cNQ * (cHEADS / 4), 256, 0, stream>>>(pq, pk, pv, pts, ao);
  proj_rows_k<<<cB * cNQ, 256, 0, stream>>>(ao, Wo, bo, out, 1.0f);
}

// Round 2
// 500.887 us; speedup vs baseline: 1.6993x; 1.6993x over previous
//
#include <hip/hip_runtime.h>
#include <hip/hip_bf16.h>
#include <math.h>

constexpr int cB = 8, cNQ = 300, cC = 256, cH = 64, cW = 64, cHEADS = 8, cHD = 32;
constexpr int cHW = cH * cW;
constexpr float cSCALE = 0.1767766952966369f; // 32^-0.5

// out[m,n] = (dot(X[m,:], Wt[n,:]) + bias[n]) * scale   (M rows, 256x256 weight)
__global__ __launch_bounds__(256) void proj_rows_k(
    const float* __restrict__ X, const float* __restrict__ Wt,
    const float* __restrict__ bias, float* __restrict__ out, float scale) {
  __shared__ float xs[cC];
  int m = blockIdx.x;
  int n = threadIdx.x;
  xs[n] = X[(size_t)m * cC + n];
  __syncthreads();
  const float4* wrow = (const float4*)(Wt + (size_t)n * cC);
  float acc = 0.f;
#pragma unroll 8
  for (int k4 = 0; k4 < cC / 4; ++k4) {
    float4 w = wrow[k4];
    acc += xs[k4 * 4 + 0] * w.x + xs[k4 * 4 + 1] * w.y +
           xs[k4 * 4 + 2] * w.z + xs[k4 * 4 + 3] * w.w;
  }
  out[(size_t)m * cC + n] = (acc + bias[n]) * scale;
}

// Projected K/V written TRANSPOSED: outT[((b*8+head)*4096 + hw)*32 + d],
// o = head*32 + d. z = b*2 + isv.
__global__ __launch_bounds__(256) void proj_kv_k(
    const float* __restrict__ key, const float* __restrict__ value,
    const float* __restrict__ Wk, const float* __restrict__ bk,
    const float* __restrict__ Wv, const float* __restrict__ bv,
    float* __restrict__ pkT, float* __restrict__ pvT) {
  int z = blockIdx.z;
  int b = z >> 1;
  bool isv = z & 1;
  const float* X = (isv ? value : key) + (size_t)b * cC * cHW;
  const float* Wm = isv ? Wv : Wk;
  const float* bb = isv ? bv : bk;
  float* outT = (isv ? pvT : pkT) + (size_t)b * cHEADS * cHW * cHD;
  int hw0 = blockIdx.x * 128;
  int o0 = blockIdx.y * 64;

  __shared__ float As[64][20];   // Wm tile [64 o][16 c], padded
  __shared__ float Bs[16][132];  // X tile  [16 c][128 hw], padded
  __shared__ float ts[64][133];  // transpose staging [o_local][hw_local]
  int tid = threadIdx.x;
  int tx = tid & 31, ty = tid >> 5;

  float acc[8][4];
#pragma unroll
  for (int i = 0; i < 8; ++i)
#pragma unroll
    for (int j = 0; j < 4; ++j) acc[i][j] = 0.f;

  for (int c0 = 0; c0 < cC; c0 += 16) {
    {
      int row = tid >> 2, cg = (tid & 3) << 2;
      float4 v = *(const float4*)(Wm + (size_t)(o0 + row) * cC + c0 + cg);
      *(float4*)&As[row][cg] = v;
    }
    {
      int row = tid >> 4, col = (tid & 15) << 3;
      const float* src = X + (size_t)(c0 + row) * cHW + hw0 + col;
      *(float4*)&Bs[row][col] = *(const float4*)src;
      *(float4*)&Bs[row][col + 4] = *(const float4*)(src + 4);
    }
    __syncthreads();
#pragma unroll
    for (int kk = 0; kk < 16; ++kk) {
      float a[8], bv4[4];
#pragma unroll
      for (int j = 0; j < 4; ++j) bv4[j] = Bs[kk][tx + 32 * j];
#pragma unroll
      for (int i = 0; i < 8; ++i) a[i] = As[ty * 8 + i][kk];
#pragma unroll
      for (int i = 0; i < 8; ++i)
#pragma unroll
        for (int j = 0; j < 4; ++j) acc[i][j] += a[i] * bv4[j];
    }
    __syncthreads();
  }

  // stage with bias into LDS, then write transposed & coalesced
#pragma unroll
  for (int i = 0; i < 8; ++i) {
    float bias = bb[o0 + ty * 8 + i];
#pragma unroll
    for (int j = 0; j < 4; ++j) ts[ty * 8 + i][tx + 32 * j] = acc[i][j] + bias;
  }
  __syncthreads();
  int ol = tid & 63;
  int o = o0 + ol;
  int head = o >> 5, d = o & 31;
  float* obase = outT + ((size_t)head * cHW) * cHD + d;
  int hwl0 = tid >> 6;  // 0..3
#pragma unroll 8
  for (int p = 0; p < 32; ++p) {
    int hwl = hwl0 + 4 * p;
    obase[(size_t)(hw0 + hwl) * cHD] = ts[ol][hwl];
  }
}

// One wave per (b,q,head). Block = 4 waves = 4 heads; grid = B*NQ*2.
// XCD swizzle: blockIdx.x & 7 selects b so each XCD's L2 holds one batch.
__global__ __launch_bounds__(256) void attn_k(
    const float* __restrict__ pq, const float* __restrict__ pkT,
    const float* __restrict__ pvT, const float* __restrict__ pts,
    float* __restrict__ out) {
  int bid = blockIdx.x;
  int b = bid & 7;
  int rem = bid >> 3;       // 0..599
  int q = rem >> 1;
  int pair = rem & 1;
  int tid = threadIdx.x;
  int wid = tid >> 6, lane = tid & 63;
  int n = pair * 4 + wid;

  __shared__ float q_s[128];
  __shared__ float attn_s[4][2][64];
  __shared__ float sptf[2];
  __shared__ int spti[4];
  if (tid < 128) q_s[tid] = pq[((size_t)b * cNQ + q) * cC + pair * 128 + tid];
  if (tid == 0) {
    float x = pts[((size_t)b * cNQ + q) * 2 + 0];
    float y = pts[((size_t)b * cNQ + q) * 2 + 1];
    float y0f = fminf(fmaxf(floorf(y), 0.f), (float)(cH - 1));
    float x0f = fminf(fmaxf(floorf(x), 0.f), (float)(cW - 1));
    sptf[0] = y - y0f;
    sptf[1] = x - x0f;
    spti[0] = (int)y0f;
    spti[1] = min((int)y0f + 1, cH - 1);
    spti[2] = (int)x0f;
    spti[3] = min((int)x0f + 1, cW - 1);
  }
  __syncthreads();
  float wy = sptf[0], wx = sptf[1];
  int y0 = spti[0], y1 = spti[1], x0 = spti[2], x1 = spti[3];

  const float* kTb = pkT + ((size_t)(b * cHEADS + n)) * cHW * cHD;
  const float* vTb = pvT + ((size_t)(b * cHEADS + n)) * cHW * cHD;

  // ---- logits: lane = position; each lane reads its own 128B chunks ----
  const float4* kr0 = (const float4*)(kTb + (size_t)(y0 * cW + lane) * cHD);
  const float4* kr1 = (const float4*)(kTb + (size_t)(y1 * cW + lane) * cHD);
  const float4* kc0 = (const float4*)(kTb + (size_t)(lane * cW + x0) * cHD);
  const float4* kc1 = (const float4*)(kTb + (size_t)(lane * cW + x1) * cHD);
  float wrow = 0.f, wcol = 0.f;
#pragma unroll
  for (int d4 = 0; d4 < cHD / 4; ++d4) {
    float4 a0 = kr0[d4], a1 = kr1[d4];
    float4 c0 = kc0[d4], c1 = kc1[d4];
    float4 qv = *(const float4*)&q_s[wid * 32 + d4 * 4];
    wrow += qv.x * (a0.x + wy * (a1.x - a0.x)) +
            qv.y * (a0.y + wy * (a1.y - a0.y)) +
            qv.z * (a0.z + wy * (a1.z - a0.z)) +
            qv.w * (a0.w + wy * (a1.w - a0.w));
    wcol += qv.x * (c0.x + wx * (c1.x - c0.x)) +
            qv.y * (c0.y + wx * (c1.y - c0.y)) +
            qv.z * (c0.z + wx * (c1.z - c0.z)) +
            qv.w * (c0.w + wx * (c1.w - c0.w));
  }

  // ---- softmax over 128 values (2 per lane) ----
  float m = fmaxf(wrow, wcol);
#pragma unroll
  for (int s = 32; s > 0; s >>= 1) m = fmaxf(m, __shfl_xor(m, s, 64));
  float er = expf(wrow - m), ec = expf(wcol - m);
  float ssum = er + ec;
#pragma unroll
  for (int s = 32; s > 0; s >>= 1) ssum += __shfl_xor(ssum, s, 64);
  float inv = 1.f / ssum;
  attn_s[wid][0][lane] = er * inv;
  attn_s[wid][1][lane] = ec * inv;
  __syncthreads();

  // ---- PV: lane -> (d = lane&31, half = lane>>5); coalesced 128B segments ----
  int d = lane & 31, half = lane >> 5;
  const float* vr0 = vTb + (size_t)(y0 * cW) * cHD + d;
  const float* vr1 = vTb + (size_t)(y1 * cW) * cHD + d;
  const float* vc0 = vTb + (size_t)x0 * cHD + d;
  const float* vc1 = vTb + (size_t)x1 * cHD + d;
  float acc = 0.f;
#pragma unroll 8
  for (int j = 0; j < 32; ++j) {
    int pos = half * 32 + j;
    float ar = attn_s[wid][0][pos], ac = attn_s[wid][1][pos];
    float r0 = vr0[(size_t)pos * cHD], r1 = vr1[(size_t)pos * cHD];
    float c0 = vc0[(size_t)pos * cW * cHD], c1 = vc1[(size_t)pos * cW * cHD];
    acc += ar * (r0 + wy * (r1 - r0)) + ac * (c0 + wx * (c1 - c0));
  }
  acc += __shfl_xor(acc, 32, 64);
  if (lane < 32) out[((size_t)b * cNQ + q) * cC + n * cHD + d] = acc;
}

extern "C" void kernel_launch(void* const* d_in, const int* in_sizes, int n_in,
                              void* d_out, int out_size, void* d_ws, size_t ws_size,
                              hipStream_t stream) {
  const float* query = (const float*)d_in[0];
  const float* key   = (const float*)d_in[1];
  const float* value = (const float*)d_in[2];
  const float* pts   = (const float*)d_in[3];
  const float* Wq = (const float*)d_in[4];
  const float* bq = (const float*)d_in[5];
  const float* Wk = (const float*)d_in[6];
  const float* bk = (const float*)d_in[7];
  const float* Wv = (const float*)d_in[8];
  const float* bv = (const float*)d_in[9];
  const float* Wo = (const float*)d_in[10];
  const float* bo = (const float*)d_in[11];
  float* out = (float*)d_out;

  float* pq = (float*)d_ws;                         // 614400
  float* pkT = pq + (size_t)cB * cNQ * cC;          // 8388608 (transposed [b,h,hw,d])
  float* pvT = pkT + (size_t)cB * cC * cHW;         // 8388608
  float* ao = pvT + (size_t)cB * cC * cHW;          // 614400

  proj_rows_k<<<cB * cNQ, 256, 0, stream>>>(query, Wq, bq, pq, cSCALE);
  proj_kv_k<<<dim3(cHW / 128, cC / 64, cB * 2), 256, 0, stream>>>(
      key, value, Wk, bk, Wv, bv, pkT, pvT);
  attn_k<<<cB * cNQ * 2, 256, 0, stream>>>(pq, pkT, pvT, pts, ao);
  proj_rows_k<<<cB * cNQ, 256, 0, stream>>>(ao, Wo, bo, out, 1.0f);
}

// Round 3
// 445.166 us; speedup vs baseline: 1.9120x; 1.1252x over previous
//
#include <hip/hip_runtime.h>
#include <hip/hip_bf16.h>
#include <math.h>

constexpr int cB = 8, cNQ = 300, cC = 256, cH = 64, cW = 64, cHEADS = 8, cHD = 32;
constexpr int cHW = cH * cW;
constexpr float cSCALE = 0.1767766952966369f; // 32^-0.5

// out[m,n] = (dot(X[m,:], Wt[n,:]) + bias[n]) * scale   (M rows, 256x256 weight)
__global__ __launch_bounds__(256) void proj_rows_k(
    const float* __restrict__ X, const float* __restrict__ Wt,
    const float* __restrict__ bias, float* __restrict__ out, float scale) {
  __shared__ float xs[cC];
  int m = blockIdx.x;
  int n = threadIdx.x;
  xs[n] = X[(size_t)m * cC + n];
  __syncthreads();
  const float4* wrow = (const float4*)(Wt + (size_t)n * cC);
  float acc = 0.f;
#pragma unroll 8
  for (int k4 = 0; k4 < cC / 4; ++k4) {
    float4 w = wrow[k4];
    acc += xs[k4 * 4 + 0] * w.x + xs[k4 * 4 + 1] * w.y +
           xs[k4 * 4 + 2] * w.z + xs[k4 * 4 + 3] * w.w;
  }
  out[(size_t)m * cC + n] = (acc + bias[n]) * scale;
}

// Projected K/V written TRANSPOSED: outT[((b*8+head)*4096 + hw)*32 + d],
// o = head*32 + d. z = b*2 + isv.
__global__ __launch_bounds__(256) void proj_kv_k(
    const float* __restrict__ key, const float* __restrict__ value,
    const float* __restrict__ Wk, const float* __restrict__ bk,
    const float* __restrict__ Wv, const float* __restrict__ bv,
    float* __restrict__ pkT, float* __restrict__ pvT) {
  int z = blockIdx.z;
  int b = z >> 1;
  bool isv = z & 1;
  const float* X = (isv ? value : key) + (size_t)b * cC * cHW;
  const float* Wm = isv ? Wv : Wk;
  const float* bb = isv ? bv : bk;
  float* outT = (isv ? pvT : pkT) + (size_t)b * cHEADS * cHW * cHD;
  int hw0 = blockIdx.x * 128;
  int o0 = blockIdx.y * 64;

  __shared__ float As[64][20];   // Wm tile [64 o][16 c], padded
  __shared__ float Bs[16][132];  // X tile  [16 c][128 hw], padded
  __shared__ float ts[64][133];  // transpose staging [o_local][hw_local]
  int tid = threadIdx.x;
  int tx = tid & 31, ty = tid >> 5;

  float acc[8][4];
#pragma unroll
  for (int i = 0; i < 8; ++i)
#pragma unroll
    for (int j = 0; j < 4; ++j) acc[i][j] = 0.f;

  for (int c0 = 0; c0 < cC; c0 += 16) {
    {
      int row = tid >> 2, cg = (tid & 3) << 2;
      float4 v = *(const float4*)(Wm + (size_t)(o0 + row) * cC + c0 + cg);
      *(float4*)&As[row][cg] = v;
    }
    {
      int row = tid >> 4, col = (tid & 15) << 3;
      const float* src = X + (size_t)(c0 + row) * cHW + hw0 + col;
      *(float4*)&Bs[row][col] = *(const float4*)src;
      *(float4*)&Bs[row][col + 4] = *(const float4*)(src + 4);
    }
    __syncthreads();
#pragma unroll
    for (int kk = 0; kk < 16; ++kk) {
      float a[8], bv4[4];
#pragma unroll
      for (int j = 0; j < 4; ++j) bv4[j] = Bs[kk][tx + 32 * j];
#pragma unroll
      for (int i = 0; i < 8; ++i) a[i] = As[ty * 8 + i][kk];
#pragma unroll
      for (int i = 0; i < 8; ++i)
#pragma unroll
        for (int j = 0; j < 4; ++j) acc[i][j] += a[i] * bv4[j];
    }
    __syncthreads();
  }

  // stage with bias into LDS, then write transposed & coalesced
#pragma unroll
  for (int i = 0; i < 8; ++i) {
    float bias = bb[o0 + ty * 8 + i];
#pragma unroll
    for (int j = 0; j < 4; ++j) ts[ty * 8 + i][tx + 32 * j] = acc[i][j] + bias;
  }
  __syncthreads();
  int ol = tid & 63;
  int o = o0 + ol;
  int head = o >> 5, d = o & 31;
  float* obase = outT + ((size_t)head * cHW) * cHD + d;
  int hwl0 = tid >> 6;  // 0..3
#pragma unroll 8
  for (int p = 0; p < 32; ++p) {
    int hwl = hwl0 + 4 * p;
    obase[(size_t)(hw0 + hwl) * cHD] = ts[ol][hwl];
  }
}

// One wave per (b,q,head). Block = 4 waves = 4 heads.
// Phase-scheduled XCD swizzle: xcd = bid&7; group g = xcd + 8*(t>=300).
// g -> (b = g>>1, pair = g&1): per-XCD working set = 4 heads K+V = 4 MB (fits L2).
__global__ __launch_bounds__(256) void attn_k(
    const float* __restrict__ pq, const float* __restrict__ pkT,
    const float* __restrict__ pvT, const float* __restrict__ pts,
    float* __restrict__ out) {
  int bid = blockIdx.x;
  int xcd = bid & 7;
  int t = bid >> 3;                 // 0..599
  int phase = (t >= cNQ) ? 1 : 0;
  int q = t - phase * cNQ;
  int g = xcd + 8 * phase;          // 0..15
  int b = g >> 1;
  int pair = g & 1;
  int tid = threadIdx.x;
  int wid = tid >> 6, lane = tid & 63;
  int n = pair * 4 + wid;

  __shared__ float q_s[128];
  __shared__ float attn_s[4][2][64];
  __shared__ float sptf[2];
  __shared__ int spti[4];
  if (tid < 128) q_s[tid] = pq[((size_t)b * cNQ + q) * cC + pair * 128 + tid];
  if (tid == 0) {
    float x = pts[((size_t)b * cNQ + q) * 2 + 0];
    float y = pts[((size_t)b * cNQ + q) * 2 + 1];
    float y0f = fminf(fmaxf(floorf(y), 0.f), (float)(cH - 1));
    float x0f = fminf(fmaxf(floorf(x), 0.f), (float)(cW - 1));
    sptf[0] = y - y0f;
    sptf[1] = x - x0f;
    spti[0] = (int)y0f;
    spti[1] = min((int)y0f + 1, cH - 1);
    spti[2] = (int)x0f;
    spti[3] = min((int)x0f + 1, cW - 1);
  }
  __syncthreads();
  float wy = sptf[0], wx = sptf[1];
  int y0 = spti[0], y1 = spti[1], x0 = spti[2], x1 = spti[3];

  const float* kTb = pkT + ((size_t)(b * cHEADS + n)) * cHW * cHD;
  const float* vTb = pvT + ((size_t)(b * cHEADS + n)) * cHW * cHD;

  // ---- logits: lane = position; each lane reads its own 128B chunks ----
  const float4* kr0 = (const float4*)(kTb + (size_t)(y0 * cW + lane) * cHD);
  const float4* kr1 = (const float4*)(kTb + (size_t)(y1 * cW + lane) * cHD);
  const float4* kc0 = (const float4*)(kTb + (size_t)(lane * cW + x0) * cHD);
  const float4* kc1 = (const float4*)(kTb + (size_t)(lane * cW + x1) * cHD);
  float wrow = 0.f, wcol = 0.f;
#pragma unroll
  for (int d4 = 0; d4 < cHD / 4; ++d4) {
    float4 a0 = kr0[d4], a1 = kr1[d4];
    float4 c0 = kc0[d4], c1 = kc1[d4];
    float4 qv = *(const float4*)&q_s[wid * 32 + d4 * 4];
    wrow += qv.x * (a0.x + wy * (a1.x - a0.x)) +
            qv.y * (a0.y + wy * (a1.y - a0.y)) +
            qv.z * (a0.z + wy * (a1.z - a0.z)) +
            qv.w * (a0.w + wy * (a1.w - a0.w));
    wcol += qv.x * (c0.x + wx * (c1.x - c0.x)) +
            qv.y * (c0.y + wx * (c1.y - c0.y)) +
            qv.z * (c0.z + wx * (c1.z - c0.z)) +
            qv.w * (c0.w + wx * (c1.w - c0.w));
  }

  // ---- softmax over 128 values (2 per lane) ----
  float m = fmaxf(wrow, wcol);
#pragma unroll
  for (int s = 32; s > 0; s >>= 1) m = fmaxf(m, __shfl_xor(m, s, 64));
  float er = expf(wrow - m), ec = expf(wcol - m);
  float ssum = er + ec;
#pragma unroll
  for (int s = 32; s > 0; s >>= 1) ssum += __shfl_xor(ssum, s, 64);
  float inv = 1.f / ssum;
  attn_s[wid][0][lane] = er * inv;
  attn_s[wid][1][lane] = ec * inv;
  __syncthreads();

  // ---- PV: lane = (pos-group g8 = lane>>3, d-chunk c = lane&7) ----
  // Each lane accumulates one float4 d-chunk over 8 positions; 3-step butterfly.
  int g8 = lane >> 3, c4 = (lane & 7) * 4;
  float4 acc = make_float4(0.f, 0.f, 0.f, 0.f);
#pragma unroll
  for (int k = 0; k < 8; ++k) {
    int pos = g8 * 8 + k;
    float ar = attn_s[wid][0][pos], ac = attn_s[wid][1][pos];
    float4 r0 = *(const float4*)(vTb + (size_t)(y0 * cW + pos) * cHD + c4);
    float4 r1 = *(const float4*)(vTb + (size_t)(y1 * cW + pos) * cHD + c4);
    float4 c0 = *(const float4*)(vTb + (size_t)(pos * cW + x0) * cHD + c4);
    float4 c1 = *(const float4*)(vTb + (size_t)(pos * cW + x1) * cHD + c4);
    acc.x += ar * (r0.x + wy * (r1.x - r0.x)) + ac * (c0.x + wx * (c1.x - c0.x));
    acc.y += ar * (r0.y + wy * (r1.y - r0.y)) + ac * (c0.y + wx * (c1.y - c0.y));
    acc.z += ar * (r0.z + wy * (r1.z - r0.z)) + ac * (c0.z + wx * (c1.z - c0.z));
    acc.w += ar * (r0.w + wy * (r1.w - r0.w)) + ac * (c0.w + wx * (c1.w - c0.w));
  }
#pragma unroll
  for (int s = 8; s <= 32; s <<= 1) {
    acc.x += __shfl_xor(acc.x, s, 64);
    acc.y += __shfl_xor(acc.y, s, 64);
    acc.z += __shfl_xor(acc.z, s, 64);
    acc.w += __shfl_xor(acc.w, s, 64);
  }
  if (lane < 8)
    *(float4*)(out + ((size_t)b * cNQ + q) * cC + n * cHD + lane * 4) = acc;
}

extern "C" void kernel_launch(void* const* d_in, const int* in_sizes, int n_in,
                              void* d_out, int out_size, void* d_ws, size_t ws_size,
                              hipStream_t stream) {
  const float* query = (const float*)d_in[0];
  const float* key   = (const float*)d_in[1];
  const float* value = (const float*)d_in[2];
  const float* pts   = (const float*)d_in[3];
  const float* Wq = (const float*)d_in[4];
  const float* bq = (const float*)d_in[5];
  const float* Wk = (const float*)d_in[6];
  const float* bk = (const float*)d_in[7];
  const float* Wv = (const float*)d_in[8];
  const float* bv = (const float*)d_in[9];
  const float* Wo = (const float*)d_in[10];
  const float* bo = (const float*)d_in[11];
  float* out = (float*)d_out;

  float* pq = (float*)d_ws;                         // 614400
  float* pkT = pq + (size_t)cB * cNQ * cC;          // 8388608 (transposed [b,h,hw,d])
  float* pvT = pkT + (size_t)cB * cC * cHW;         // 8388608
  float* ao = pvT + (size_t)cB * cC * cHW;          // 614400

  proj_rows_k<<<cB * cNQ, 256, 0, stream>>>(query, Wq, bq, pq, cSCALE);
  proj_kv_k<<<dim3(cHW / 128, cC / 64, cB * 2), 256, 0, stream>>>(
      key, value, Wk, bk, Wv, bv, pkT, pvT);
  attn_k<<<cB * cNQ * 2, 256, 0, stream>>>(pq, pkT, pvT, pts, ao);
  proj_rows_k<<<cB * cNQ, 256, 0, stream>>>(ao, Wo, bo, out, 1.0f);
}

// Round 4
// 331.400 us; speedup vs baseline: 2.5683x; 1.3433x over previous
//
#include <hip/hip_runtime.h>
#include <hip/hip_bf16.h>
#include <math.h>

constexpr int cB = 8, cNQ = 300, cC = 256, cH = 64, cW = 64, cHEADS = 8, cHD = 32;
constexpr int cHW = cH * cW;
constexpr float cSCALE = 0.1767766952966369f; // 32^-0.5

typedef __bf16 bf16_t;
typedef bf16_t bf16x4 __attribute__((ext_vector_type(4)));
typedef bf16_t bf16x8 __attribute__((ext_vector_type(8)));
typedef float f32x4 __attribute__((ext_vector_type(4)));

// out[m,n] = (dot(X[m,:], Wt[n,:]) + bias[n]) * scale   (M rows, 256x256 weight)
__global__ __launch_bounds__(256) void proj_rows_k(
    const float* __restrict__ X, const float* __restrict__ Wt,
    const float* __restrict__ bias, float* __restrict__ out, float scale) {
  __shared__ float xs[cC];
  int m = blockIdx.x;
  int n = threadIdx.x;
  xs[n] = X[(size_t)m * cC + n];
  __syncthreads();
  const float4* wrow = (const float4*)(Wt + (size_t)n * cC);
  float acc = 0.f;
#pragma unroll 8
  for (int k4 = 0; k4 < cC / 4; ++k4) {
    float4 w = wrow[k4];
    acc += xs[k4 * 4 + 0] * w.x + xs[k4 * 4 + 1] * w.y +
           xs[k4 * 4 + 2] * w.z + xs[k4 * 4 + 3] * w.w;
  }
  out[(size_t)m * cC + n] = (acc + bias[n]) * scale;
}

// bf16-MFMA K/V projection, writing TRANSPOSED layout directly:
// outT[((b*8+head)*4096 + hw)*32 + d] = sum_c W[o,c]*X[b,c,hw] + bias[o],
// o = head*32+d.  D[hw][o] = A(X^T) * B(W^T).  z = b*2 + isv.
__global__ __launch_bounds__(256) void proj_kv_mfma_k(
    const float* __restrict__ key, const float* __restrict__ value,
    const float* __restrict__ Wk, const float* __restrict__ bk,
    const float* __restrict__ Wv, const float* __restrict__ bv,
    float* __restrict__ pkT, float* __restrict__ pvT) {
  int z = blockIdx.z;
  int b = z >> 1;
  bool isv = z & 1;
  const float* X = (isv ? value : key) + (size_t)b * cC * cHW;
  const float* Wm = isv ? Wv : Wk;
  const float* bb = isv ? bv : bk;
  float* outT = (isv ? pvT : pkT) + (size_t)b * cHEADS * cHW * cHD;
  int hw0 = blockIdx.x * 128;
  int o0 = blockIdx.y * 64;

  // XOR-swizzled bf16 tiles: idx = row*64 + (col ^ ((row&7)*8))
  __shared__ bf16_t Xs[128 * 64];  // X^T tile [hw][c]
  __shared__ bf16_t Ws[64 * 64];   // W tile  [o][c]

  int tid = threadIdx.x;
  int lane = tid & 63, w = tid >> 6;
  int hwl = (w & 1) * 64 + lane;      // X staging row (hw-local)
  int cbase = (w >> 1) * 32;          // X staging c-range base
  int wo_l = tid >> 2;                // W staging o-local (0..63)
  int wcg = (tid & 3) * 16;           // W staging c-group
  int hwoff = (w & 1) * 64, ooff = (w >> 1) * 32;  // wave output sub-tile
  int l15 = lane & 15, l4 = lane >> 4;

  f32x4 acc[4][2];
#pragma unroll
  for (int m = 0; m < 4; ++m)
#pragma unroll
    for (int n = 0; n < 2; ++n) acc[m][n] = (f32x4){0.f, 0.f, 0.f, 0.f};

  for (int c0 = 0; c0 < cC; c0 += 64) {
    // ---- stage X^T: strided-c dword loads (coalesced across lanes in hw),
    //      pack 4 c-vals -> 8B swizzled ds_write ----
    const float* xcol = X + (size_t)(c0 + cbase) * cHW + hw0 + hwl;
#pragma unroll
    for (int i = 0; i < 8; ++i) {
      float f0 = xcol[(size_t)(i * 4 + 0) * cHW];
      float f1 = xcol[(size_t)(i * 4 + 1) * cHW];
      float f2 = xcol[(size_t)(i * 4 + 2) * cHW];
      float f3 = xcol[(size_t)(i * 4 + 3) * cHW];
      bf16x4 v = {(bf16_t)f0, (bf16_t)f1, (bf16_t)f2, (bf16_t)f3};
      int c_l = cbase + i * 4;
      *(bf16x4*)&Xs[hwl * 64 + (c_l ^ ((hwl & 7) * 8))] = v;
    }
    // ---- stage W: row-major float4 loads, 2x 16B swizzled ds_writes ----
    {
      const float4* wrow = (const float4*)(Wm + (size_t)(o0 + wo_l) * cC + c0 + wcg);
      float4 a = wrow[0], b4 = wrow[1], c4 = wrow[2], d4 = wrow[3];
      bf16x8 w0 = {(bf16_t)a.x, (bf16_t)a.y, (bf16_t)a.z, (bf16_t)a.w,
                   (bf16_t)b4.x, (bf16_t)b4.y, (bf16_t)b4.z, (bf16_t)b4.w};
      bf16x8 w1 = {(bf16_t)c4.x, (bf16_t)c4.y, (bf16_t)c4.z, (bf16_t)c4.w,
                   (bf16_t)d4.x, (bf16_t)d4.y, (bf16_t)d4.z, (bf16_t)d4.w};
      int sw = (wo_l & 7) * 8;
      *(bf16x8*)&Ws[wo_l * 64 + (wcg ^ sw)] = w0;
      *(bf16x8*)&Ws[wo_l * 64 + ((wcg + 8) ^ sw)] = w1;
    }
    __syncthreads();
    // ---- 2 k-steps x 8 MFMA ----
#pragma unroll
    for (int s = 0; s < 2; ++s) {
      int c8 = s * 32 + l4 * 8;
      bf16x8 afr[4], bfr[2];
#pragma unroll
      for (int m = 0; m < 4; ++m) {
        int r = hwoff + m * 16 + l15;
        afr[m] = *(const bf16x8*)&Xs[r * 64 + (c8 ^ ((r & 7) * 8))];
      }
#pragma unroll
      for (int n = 0; n < 2; ++n) {
        int r = ooff + n * 16 + l15;
        bfr[n] = *(const bf16x8*)&Ws[r * 64 + (c8 ^ ((r & 7) * 8))];
      }
#pragma unroll
      for (int m = 0; m < 4; ++m)
#pragma unroll
        for (int n = 0; n < 2; ++n)
          acc[m][n] = __builtin_amdgcn_mfma_f32_16x16x32_bf16(
              afr[m], bfr[n], acc[m][n], 0, 0, 0);
    }
    __syncthreads();
  }

  // ---- epilogue: D[hw][o] -> outT[hw][d] direct (o0+ooff multiple of 32) ----
  int head = (o0 + ooff) >> 5;
  float* obase = outT + (size_t)head * cHW * cHD;
  float bias0 = bb[o0 + ooff + l15];
  float bias1 = bb[o0 + ooff + 16 + l15];
#pragma unroll
  for (int m = 0; m < 4; ++m) {
    int hwr = hwoff + m * 16 + l4 * 4;
#pragma unroll
    for (int reg = 0; reg < 4; ++reg) {
      size_t rowoff = (size_t)(hw0 + hwr + reg) * cHD;
      obase[rowoff + l15] = acc[m][0][reg] + bias0;
      obase[rowoff + 16 + l15] = acc[m][1][reg] + bias1;
    }
  }
}

// One wave per (b,q,head). Block = 4 waves = 4 heads.
// Phase-scheduled XCD swizzle: xcd = bid&7; group g = xcd + 8*(t>=300).
// g -> (b = g>>1, pair = g&1): per-XCD working set = 4 heads K+V = 4 MB (fits L2).
__global__ __launch_bounds__(256) void attn_k(
    const float* __restrict__ pq, const float* __restrict__ pkT,
    const float* __restrict__ pvT, const float* __restrict__ pts,
    float* __restrict__ out) {
  int bid = blockIdx.x;
  int xcd = bid & 7;
  int t = bid >> 3;                 // 0..599
  int phase = (t >= cNQ) ? 1 : 0;
  int q = t - phase * cNQ;
  int g = xcd + 8 * phase;          // 0..15
  int b = g >> 1;
  int pair = g & 1;
  int tid = threadIdx.x;
  int wid = tid >> 6, lane = tid & 63;
  int n = pair * 4 + wid;

  __shared__ float q_s[128];
  __shared__ float attn_s[4][2][64];
  __shared__ float sptf[2];
  __shared__ int spti[4];
  if (tid < 128) q_s[tid] = pq[((size_t)b * cNQ + q) * cC + pair * 128 + tid];
  if (tid == 0) {
    float x = pts[((size_t)b * cNQ + q) * 2 + 0];
    float y = pts[((size_t)b * cNQ + q) * 2 + 1];
    float y0f = fminf(fmaxf(floorf(y), 0.f), (float)(cH - 1));
    float x0f = fminf(fmaxf(floorf(x), 0.f), (float)(cW - 1));
    sptf[0] = y - y0f;
    sptf[1] = x - x0f;
    spti[0] = (int)y0f;
    spti[1] = min((int)y0f + 1, cH - 1);
    spti[2] = (int)x0f;
    spti[3] = min((int)x0f + 1, cW - 1);
  }
  __syncthreads();
  float wy = sptf[0], wx = sptf[1];
  int y0 = spti[0], y1 = spti[1], x0 = spti[2], x1 = spti[3];

  const float* kTb = pkT + ((size_t)(b * cHEADS + n)) * cHW * cHD;
  const float* vTb = pvT + ((size_t)(b * cHEADS + n)) * cHW * cHD;

  // ---- logits: lane = position; each lane reads its own 128B chunks ----
  const float4* kr0 = (const float4*)(kTb + (size_t)(y0 * cW + lane) * cHD);
  const float4* kr1 = (const float4*)(kTb + (size_t)(y1 * cW + lane) * cHD);
  const float4* kc0 = (const float4*)(kTb + (size_t)(lane * cW + x0) * cHD);
  const float4* kc1 = (const float4*)(kTb + (size_t)(lane * cW + x1) * cHD);
  float wrow = 0.f, wcol = 0.f;
#pragma unroll
  for (int d4 = 0; d4 < cHD / 4; ++d4) {
    float4 a0 = kr0[d4], a1 = kr1[d4];
    float4 c0 = kc0[d4], c1 = kc1[d4];
    float4 qv = *(const float4*)&q_s[wid * 32 + d4 * 4];
    wrow += qv.x * (a0.x + wy * (a1.x - a0.x)) +
            qv.y * (a0.y + wy * (a1.y - a0.y)) +
            qv.z * (a0.z + wy * (a1.z - a0.z)) +
            qv.w * (a0.w + wy * (a1.w - a0.w));
    wcol += qv.x * (c0.x + wx * (c1.x - c0.x)) +
            qv.y * (c0.y + wx * (c1.y - c0.y)) +
            qv.z * (c0.z + wx * (c1.z - c0.z)) +
            qv.w * (c0.w + wx * (c1.w - c0.w));
  }

  // ---- softmax over 128 values (2 per lane) ----
  float m = fmaxf(wrow, wcol);
#pragma unroll
  for (int s = 32; s > 0; s >>= 1) m = fmaxf(m, __shfl_xor(m, s, 64));
  float er = expf(wrow - m), ec = expf(wcol - m);
  float ssum = er + ec;
#pragma unroll
  for (int s = 32; s > 0; s >>= 1) ssum += __shfl_xor(ssum, s, 64);
  float inv = 1.f / ssum;
  attn_s[wid][0][lane] = er * inv;
  attn_s[wid][1][lane] = ec * inv;
  __syncthreads();

  // ---- PV: lane = (pos-group g8 = lane>>3, d-chunk c = lane&7) ----
  int g8 = lane >> 3, c4 = (lane & 7) * 4;
  float4 acc = make_float4(0.f, 0.f, 0.f, 0.f);
#pragma unroll
  for (int k = 0; k < 8; ++k) {
    int pos = g8 * 8 + k;
    float ar = attn_s[wid][0][pos], ac = attn_s[wid][1][pos];
    float4 r0 = *(const float4*)(vTb + (size_t)(y0 * cW + pos) * cHD + c4);
    float4 r1 = *(const float4*)(vTb + (size_t)(y1 * cW + pos) * cHD + c4);
    float4 c0 = *(const float4*)(vTb + (size_t)(pos * cW + x0) * cHD + c4);
    float4 c1 = *(const float4*)(vTb + (size_t)(pos * cW + x1) * cHD + c4);
    acc.x += ar * (r0.x + wy * (r1.x - r0.x)) + ac * (c0.x + wx * (c1.x - c0.x));
    acc.y += ar * (r0.y + wy * (r1.y - r0.y)) + ac * (c0.y + wx * (c1.y - c0.y));
    acc.z += ar * (r0.z + wy * (r1.z - r0.z)) + ac * (c0.z + wx * (c1.z - c0.z));
    acc.w += ar * (r0.w + wy * (r1.w - r0.w)) + ac * (c0.w + wx * (c1.w - c0.w));
  }
#pragma unroll
  for (int s = 8; s <= 32; s <<= 1) {
    acc.x += __shfl_xor(acc.x, s, 64);
    acc.y += __shfl_xor(acc.y, s, 64);
    acc.z += __shfl_xor(acc.z, s, 64);
    acc.w += __shfl_xor(acc.w, s, 64);
  }
  if (lane < 8)
    *(float4*)(out + ((size_t)b * cNQ + q) * cC + n * cHD + lane * 4) = acc;
}

extern "C" void kernel_launch(void* const* d_in, const int* in_sizes, int n_in,
                              void* d_out, int out_size, void* d_ws, size_t ws_size,
                              hipStream_t stream) {
  const float* query = (const float*)d_in[0];
  const float* key   = (const float*)d_in[1];
  const float* value = (const float*)d_in[2];
  const float* pts   = (const float*)d_in[3];
  const float* Wq = (const float*)d_in[4];
  const float* bq = (const float*)d_in[5];
  const float* Wk = (const float*)d_in[6];
  const float* bk = (const float*)d_in[7];
  const float* Wv = (const float*)d_in[8];
  const float* bv = (const float*)d_in[9];
  const float* Wo = (const float*)d_in[10];
  const float* bo = (const float*)d_in[11];
  float* out = (float*)d_out;

  float* pq = (float*)d_ws;                         // 614400
  float* pkT = pq + (size_t)cB * cNQ * cC;          // 8388608 (transposed [b,h,hw,d])
  float* pvT = pkT + (size_t)cB * cC * cHW;         // 8388608
  float* ao = pvT + (size_t)cB * cC * cHW;          // 614400

  proj_rows_k<<<cB * cNQ, 256, 0, stream>>>(query, Wq, bq, pq, cSCALE);
  proj_kv_mfma_k<<<dim3(cHW / 128, cC / 64, cB * 2), 256, 0, stream>>>(
      key, value, Wk, bk, Wv, bv, pkT, pvT);
  attn_k<<<cB * cNQ * 2, 256, 0, stream>>>(pq, pkT, pvT, pts, ao);
  proj_rows_k<<<cB * cNQ, 256, 0, stream>>>(ao, Wo, bo, out, 1.0f);
}

// Round 5
// 243.491 us; speedup vs baseline: 3.4956x; 1.3610x over previous
//
#include <hip/hip_runtime.h>
#include <hip/hip_bf16.h>
#include <math.h>

constexpr int cB = 8, cNQ = 300, cC = 256, cH = 64, cW = 64, cHEADS = 8, cHD = 32;
constexpr int cHW = cH * cW;
constexpr float cSCALE = 0.1767766952966369f; // 32^-0.5

typedef __bf16 bf16_t;
typedef bf16_t bf16x4 __attribute__((ext_vector_type(4)));
typedef bf16_t bf16x8 __attribute__((ext_vector_type(8)));
typedef float f32x4 __attribute__((ext_vector_type(4)));
typedef _Float16 f16_t;
typedef f16_t f16x8 __attribute__((ext_vector_type(8)));

// out[m,n] = (dot(X[m,:], Wt[n,:]) + bias[n]) * scale   (M rows, 256x256 weight)
__global__ __launch_bounds__(256) void proj_rows_k(
    const float* __restrict__ X, const float* __restrict__ Wt,
    const float* __restrict__ bias, float* __restrict__ out, float scale) {
  __shared__ float xs[cC];
  int m = blockIdx.x;
  int n = threadIdx.x;
  xs[n] = X[(size_t)m * cC + n];
  __syncthreads();
  const float4* wrow = (const float4*)(Wt + (size_t)n * cC);
  float acc = 0.f;
#pragma unroll 8
  for (int k4 = 0; k4 < cC / 4; ++k4) {
    float4 w = wrow[k4];
    acc += xs[k4 * 4 + 0] * w.x + xs[k4 * 4 + 1] * w.y +
           xs[k4 * 4 + 2] * w.z + xs[k4 * 4 + 3] * w.w;
  }
  out[(size_t)m * cC + n] = (acc + bias[n]) * scale;
}

// bf16-MFMA K/V projection, writing TRANSPOSED fp16 layout directly:
// outT[((b*8+head)*4096 + hw)*32 + d] = sum_c W[o,c]*X[b,c,hw] + bias[o].
__global__ __launch_bounds__(256) void proj_kv_mfma_k(
    const float* __restrict__ key, const float* __restrict__ value,
    const float* __restrict__ Wk, const float* __restrict__ bk,
    const float* __restrict__ Wv, const float* __restrict__ bv,
    f16_t* __restrict__ pkT, f16_t* __restrict__ pvT) {
  int z = blockIdx.z;
  int b = z >> 1;
  bool isv = z & 1;
  const float* X = (isv ? value : key) + (size_t)b * cC * cHW;
  const float* Wm = isv ? Wv : Wk;
  const float* bb = isv ? bv : bk;
  f16_t* outT = (isv ? pvT : pkT) + (size_t)b * cHEADS * cHW * cHD;
  int hw0 = blockIdx.x * 128;
  int o0 = blockIdx.y * 64;

  // XOR-swizzled bf16 tiles: idx = row*64 + (col ^ ((row&7)*8))
  __shared__ bf16_t Xs[128 * 64];  // X^T tile [hw][c]
  __shared__ bf16_t Ws[64 * 64];   // W tile  [o][c]

  int tid = threadIdx.x;
  int lane = tid & 63, w = tid >> 6;
  int hwl = (w & 1) * 64 + lane;      // X staging row (hw-local)
  int cbase = (w >> 1) * 32;          // X staging c-range base
  int wo_l = tid >> 2;                // W staging o-local (0..63)
  int wcg = (tid & 3) * 16;           // W staging c-group
  int hwoff = (w & 1) * 64, ooff = (w >> 1) * 32;  // wave output sub-tile
  int l15 = lane & 15, l4 = lane >> 4;

  f32x4 acc[4][2];
#pragma unroll
  for (int m = 0; m < 4; ++m)
#pragma unroll
    for (int n = 0; n < 2; ++n) acc[m][n] = (f32x4){0.f, 0.f, 0.f, 0.f};

  for (int c0 = 0; c0 < cC; c0 += 64) {
    const float* xcol = X + (size_t)(c0 + cbase) * cHW + hw0 + hwl;
#pragma unroll
    for (int i = 0; i < 8; ++i) {
      float f0 = xcol[(size_t)(i * 4 + 0) * cHW];
      float f1 = xcol[(size_t)(i * 4 + 1) * cHW];
      float f2 = xcol[(size_t)(i * 4 + 2) * cHW];
      float f3 = xcol[(size_t)(i * 4 + 3) * cHW];
      bf16x4 v = {(bf16_t)f0, (bf16_t)f1, (bf16_t)f2, (bf16_t)f3};
      int c_l = cbase + i * 4;
      *(bf16x4*)&Xs[hwl * 64 + (c_l ^ ((hwl & 7) * 8))] = v;
    }
    {
      const float4* wrow = (const float4*)(Wm + (size_t)(o0 + wo_l) * cC + c0 + wcg);
      float4 a = wrow[0], b4 = wrow[1], c4 = wrow[2], d4 = wrow[3];
      bf16x8 w0 = {(bf16_t)a.x, (bf16_t)a.y, (bf16_t)a.z, (bf16_t)a.w,
                   (bf16_t)b4.x, (bf16_t)b4.y, (bf16_t)b4.z, (bf16_t)b4.w};
      bf16x8 w1 = {(bf16_t)c4.x, (bf16_t)c4.y, (bf16_t)c4.z, (bf16_t)c4.w,
                   (bf16_t)d4.x, (bf16_t)d4.y, (bf16_t)d4.z, (bf16_t)d4.w};
      int sw = (wo_l & 7) * 8;
      *(bf16x8*)&Ws[wo_l * 64 + (wcg ^ sw)] = w0;
      *(bf16x8*)&Ws[wo_l * 64 + ((wcg + 8) ^ sw)] = w1;
    }
    __syncthreads();
#pragma unroll
    for (int s = 0; s < 2; ++s) {
      int c8 = s * 32 + l4 * 8;
      bf16x8 afr[4], bfr[2];
#pragma unroll
      for (int m = 0; m < 4; ++m) {
        int r = hwoff + m * 16 + l15;
        afr[m] = *(const bf16x8*)&Xs[r * 64 + (c8 ^ ((r & 7) * 8))];
      }
#pragma unroll
      for (int n = 0; n < 2; ++n) {
        int r = ooff + n * 16 + l15;
        bfr[n] = *(const bf16x8*)&Ws[r * 64 + (c8 ^ ((r & 7) * 8))];
      }
#pragma unroll
      for (int m = 0; m < 4; ++m)
#pragma unroll
        for (int n = 0; n < 2; ++n)
          acc[m][n] = __builtin_amdgcn_mfma_f32_16x16x32_bf16(
              afr[m], bfr[n], acc[m][n], 0, 0, 0);
    }
    __syncthreads();
  }

  // ---- epilogue: D[hw][o] -> fp16 outT[hw][d] direct ----
  int head = (o0 + ooff) >> 5;
  f16_t* obase = outT + (size_t)head * cHW * cHD;
  float bias0 = bb[o0 + ooff + l15];
  float bias1 = bb[o0 + ooff + 16 + l15];
#pragma unroll
  for (int m = 0; m < 4; ++m) {
    int hwr = hwoff + m * 16 + l4 * 4;
#pragma unroll
    for (int reg = 0; reg < 4; ++reg) {
      size_t rowoff = (size_t)(hw0 + hwr + reg) * cHD;
      obase[rowoff + l15] = (f16_t)(acc[m][0][reg] + bias0);
      obase[rowoff + 16 + l15] = (f16_t)(acc[m][1][reg] + bias1);
    }
  }
}

// One wave per (b,q,head); waves fully independent (no LDS, no barriers).
// Phase-scheduled XCD swizzle: per-XCD working set = 4 heads fp16 K+V = 2 MB.
__global__ __launch_bounds__(256) void attn_k(
    const float* __restrict__ pq, const f16_t* __restrict__ pkT,
    const f16_t* __restrict__ pvT, const float* __restrict__ pts,
    float* __restrict__ out) {
  int bid = blockIdx.x;
  int xcd = bid & 7;
  int t = bid >> 3;                 // 0..599
  int phase = (t >= cNQ) ? 1 : 0;
  int q = t - phase * cNQ;
  int g = xcd + 8 * phase;          // 0..15
  int b = g >> 1;
  int pair = g & 1;
  int lane = threadIdx.x & 63;
  int wid = threadIdx.x >> 6;
  int n = pair * 4 + wid;

  // all lanes compute sampling params (broadcast loads)
  float x = pts[((size_t)b * cNQ + q) * 2 + 0];
  float y = pts[((size_t)b * cNQ + q) * 2 + 1];
  float y0f = fminf(fmaxf(floorf(y), 0.f), (float)(cH - 1));
  float x0f = fminf(fmaxf(floorf(x), 0.f), (float)(cW - 1));
  float wy = y - y0f, wx = x - x0f;
  int y0 = (int)y0f, y1 = min(y0 + 1, cH - 1);
  int x0 = (int)x0f, x1 = min(x0 + 1, cW - 1);

  const f16_t* kTb = pkT + (size_t)(b * cHEADS + n) * cHW * cHD;
  const f16_t* vTb = pvT + (size_t)(b * cHEADS + n) * cHW * cHD;

  // ---- early-issue PV loads (independent of QK/softmax) ----
  int g16 = lane >> 2, ch = lane & 3;
  f16x8 vr0[4], vr1[4], vc0[4], vc1[4];
#pragma unroll
  for (int k = 0; k < 4; ++k) {
    int p = g16 * 4 + k;
    vr0[k] = *(const f16x8*)(vTb + (size_t)(y0 * cW + p) * cHD + ch * 8);
    vr1[k] = *(const f16x8*)(vTb + (size_t)(y1 * cW + p) * cHD + ch * 8);
    vc0[k] = *(const f16x8*)(vTb + (size_t)(p * cW + x0) * cHD + ch * 8);
    vc1[k] = *(const f16x8*)(vTb + (size_t)(p * cW + x1) * cHD + ch * 8);
  }

  // ---- QK logits: lane = position ----
  const f16x8* kr0 = (const f16x8*)(kTb + (size_t)(y0 * cW + lane) * cHD);
  const f16x8* kr1 = (const f16x8*)(kTb + (size_t)(y1 * cW + lane) * cHD);
  const f16x8* kc0 = (const f16x8*)(kTb + (size_t)(lane * cW + x0) * cHD);
  const f16x8* kc1 = (const f16x8*)(kTb + (size_t)(lane * cW + x1) * cHD);
  const float4* qb = (const float4*)(pq + ((size_t)b * cNQ + q) * cC + n * cHD);
  float wrow = 0.f, wcol = 0.f;
#pragma unroll
  for (int c = 0; c < 4; ++c) {
    f16x8 a0 = kr0[c], a1 = kr1[c], b0 = kc0[c], b1 = kc1[c];
    float4 q0 = qb[c * 2], q1 = qb[c * 2 + 1];
    float qs[8] = {q0.x, q0.y, q0.z, q0.w, q1.x, q1.y, q1.z, q1.w};
#pragma unroll
    for (int j = 0; j < 8; ++j) {
      float f0 = (float)a0[j], f1 = (float)a1[j];
      float h0 = (float)b0[j], h1 = (float)b1[j];
      wrow += qs[j] * (f0 + wy * (f1 - f0));
      wcol += qs[j] * (h0 + wx * (h1 - h0));
    }
  }

  // ---- softmax (unnormalized; divide at the end) ----
  float m = fmaxf(wrow, wcol);
#pragma unroll
  for (int s = 32; s > 0; s >>= 1) m = fmaxf(m, __shfl_xor(m, s, 64));
  float er = expf(wrow - m), ec = expf(wcol - m);
  float ssum = er + ec;
#pragma unroll
  for (int s = 32; s > 0; s >>= 1) ssum += __shfl_xor(ssum, s, 64);

  // ---- PV: lane = (pos-group g16, d-chunk ch of 8); weights via shfl ----
  float acc[8];
#pragma unroll
  for (int j = 0; j < 8; ++j) acc[j] = 0.f;
#pragma unroll
  for (int k = 0; k < 4; ++k) {
    int p = g16 * 4 + k;
    float ar = __shfl(er, p, 64);
    float ac = __shfl(ec, p, 64);
#pragma unroll
    for (int j = 0; j < 8; ++j) {
      float r0 = (float)vr0[k][j], r1 = (float)vr1[k][j];
      float c0 = (float)vc0[k][j], c1 = (float)vc1[k][j];
      acc[j] += ar * (r0 + wy * (r1 - r0)) + ac * (c0 + wx * (c1 - c0));
    }
  }
#pragma unroll
  for (int s = 4; s <= 32; s <<= 1)
#pragma unroll
    for (int j = 0; j < 8; ++j) acc[j] += __shfl_xor(acc[j], s, 64);

  float inv = 1.f / ssum;
  if (lane < 4) {
    float* op = out + ((size_t)b * cNQ + q) * cC + n * cHD + ch * 8;
    float4 o0 = {acc[0] * inv, acc[1] * inv, acc[2] * inv, acc[3] * inv};
    float4 o1 = {acc[4] * inv, acc[5] * inv, acc[6] * inv, acc[7] * inv};
    *(float4*)op = o0;
    *(float4*)(op + 4) = o1;
  }
}

extern "C" void kernel_launch(void* const* d_in, const int* in_sizes, int n_in,
                              void* d_out, int out_size, void* d_ws, size_t ws_size,
                              hipStream_t stream) {
  const float* query = (const float*)d_in[0];
  const float* key   = (const float*)d_in[1];
  const float* value = (const float*)d_in[2];
  const float* pts   = (const float*)d_in[3];
  const float* Wq = (const float*)d_in[4];
  const float* bq = (const float*)d_in[5];
  const float* Wk = (const float*)d_in[6];
  const float* bk = (const float*)d_in[7];
  const float* Wv = (const float*)d_in[8];
  const float* bv = (const float*)d_in[9];
  const float* Wo = (const float*)d_in[10];
  const float* bo = (const float*)d_in[11];
  float* out = (float*)d_out;

  float* pq = (float*)d_ws;                         // 2400*256 f32
  f16_t* pkT = (f16_t*)(pq + (size_t)cB * cNQ * cC);  // 8*8*4096*32 f16
  f16_t* pvT = pkT + (size_t)cB * cC * cHW;
  float* ao = (float*)(pvT + (size_t)cB * cC * cHW);  // 2400*256 f32

  proj_rows_k<<<cB * cNQ, 256, 0, stream>>>(query, Wq, bq, pq, cSCALE);
  proj_kv_mfma_k<<<dim3(cHW / 128, cC / 64, cB * 2), 256, 0, stream>>>(
      key, value, Wk, bk, Wv, bv, pkT, pvT);
  attn_k<<<cB * cNQ * 2, 256, 0, stream>>>(pq, pkT, pvT, pts, ao);
  proj_rows_k<<<cB * cNQ, 256, 0, stream>>>(ao, Wo, bo, out, 1.0f);
}